// Round 1
// baseline (1487.960 us; speedup 1.0000x reference)
//
#include <hip/hip_runtime.h>

// Shapes: B=64, N=197, C=768, H=12, hd=64
// inputs: x[64,197,768] f32, table[730,12] f32, w_qkv[2304,768] f32,
//         w_proj[768,768] f32, b_proj[768] f32, rel_index[197,197] i32
// out: [64,197,768] f32

#define NB   64
#define NN   197
#define NC   768
#define NH   12
#define HD   64
#define MM   (NB*NN)      // 12608 = 197*64

// ---------------------------------------------------------------------------
// GEMM1: Y = X[M,768] * Wqkv[2304,768]^T  -> scatter to q/k/v [B,H,N,hd]
// 64x64 tile, TK=32, 256 threads, each thread 4x4.
// ---------------------------------------------------------------------------
__global__ __launch_bounds__(256) void gemm_qkv_kernel(
    const float* __restrict__ X, const float* __restrict__ W,
    float* __restrict__ qb, float* __restrict__ kb, float* __restrict__ vb)
{
    __shared__ float As[32][68];  // As[k][m]
    __shared__ float Bs[32][68];  // Bs[k][n]
    const int tid = threadIdx.x;
    const int m0 = blockIdx.x * 64;
    const int n0 = blockIdx.y * 64;
    const int lr = tid >> 2;          // 0..63 row
    const int lc = (tid & 3) << 2;    // 0,4,8,12
    const float* Ap = X + (m0 + lr) * NC + lc;
    const float* Bp = W + (n0 + lr) * NC + lc;
    const int tx = tid & 15;          // col group
    const int ty = tid >> 4;          // row group
    float acc[4][4] = {};

    for (int k0 = 0; k0 < NC; k0 += 32) {
        float4 a0 = *(const float4*)(Ap + k0);
        float4 a1 = *(const float4*)(Ap + k0 + 16);
        float4 b0 = *(const float4*)(Bp + k0);
        float4 b1 = *(const float4*)(Bp + k0 + 16);
        __syncthreads();
        As[lc+0][lr] = a0.x; As[lc+1][lr] = a0.y; As[lc+2][lr] = a0.z; As[lc+3][lr] = a0.w;
        As[lc+16][lr] = a1.x; As[lc+17][lr] = a1.y; As[lc+18][lr] = a1.z; As[lc+19][lr] = a1.w;
        Bs[lc+0][lr] = b0.x; Bs[lc+1][lr] = b0.y; Bs[lc+2][lr] = b0.z; Bs[lc+3][lr] = b0.w;
        Bs[lc+16][lr] = b1.x; Bs[lc+17][lr] = b1.y; Bs[lc+18][lr] = b1.z; Bs[lc+19][lr] = b1.w;
        __syncthreads();
        #pragma unroll
        for (int kk = 0; kk < 32; kk++) {
            float4 av = *(const float4*)&As[kk][ty << 2];
            float4 bv = *(const float4*)&Bs[kk][tx << 2];
            float a[4] = {av.x, av.y, av.z, av.w};
            float b[4] = {bv.x, bv.y, bv.z, bv.w};
            #pragma unroll
            for (int i = 0; i < 4; i++)
                #pragma unroll
                for (int j = 0; j < 4; j++)
                    acc[i][j] = fmaf(a[i], b[j], acc[i][j]);
        }
    }

    // cols n0+tx*4+j all lie in one (t,h) since n0 is 64-aligned
    const int t = blockIdx.y / 12;
    const int h = blockIdx.y % 12;
    float* dst = (t == 0) ? qb : (t == 1) ? kb : vb;
    const float scale = (t == 0) ? 0.125f : 1.0f;   // fold hd^-0.5 into q
    const int d0 = tx << 2;
    #pragma unroll
    for (int i = 0; i < 4; i++) {
        int m = m0 + (ty << 2) + i;
        int b_ = m / NN;
        int n  = m - b_ * NN;
        float4 v;
        v.x = acc[i][0] * scale; v.y = acc[i][1] * scale;
        v.z = acc[i][2] * scale; v.w = acc[i][3] * scale;
        *(float4*)&dst[((b_ * NH + h) * NN + n) * HD + d0] = v;
    }
}

// ---------------------------------------------------------------------------
// GEMM2: out = A[M,768] * Wproj[768,768]^T + bias
// ---------------------------------------------------------------------------
__global__ __launch_bounds__(256) void gemm_proj_kernel(
    const float* __restrict__ A, const float* __restrict__ W,
    const float* __restrict__ bias, float* __restrict__ out)
{
    __shared__ float As[32][68];
    __shared__ float Bs[32][68];
    const int tid = threadIdx.x;
    const int m0 = blockIdx.x * 64;
    const int n0 = blockIdx.y * 64;
    const int lr = tid >> 2;
    const int lc = (tid & 3) << 2;
    const float* Ap = A + (m0 + lr) * NC + lc;
    const float* Bp = W + (n0 + lr) * NC + lc;
    const int tx = tid & 15;
    const int ty = tid >> 4;
    float acc[4][4] = {};

    for (int k0 = 0; k0 < NC; k0 += 32) {
        float4 a0 = *(const float4*)(Ap + k0);
        float4 a1 = *(const float4*)(Ap + k0 + 16);
        float4 b0 = *(const float4*)(Bp + k0);
        float4 b1 = *(const float4*)(Bp + k0 + 16);
        __syncthreads();
        As[lc+0][lr] = a0.x; As[lc+1][lr] = a0.y; As[lc+2][lr] = a0.z; As[lc+3][lr] = a0.w;
        As[lc+16][lr] = a1.x; As[lc+17][lr] = a1.y; As[lc+18][lr] = a1.z; As[lc+19][lr] = a1.w;
        Bs[lc+0][lr] = b0.x; Bs[lc+1][lr] = b0.y; Bs[lc+2][lr] = b0.z; Bs[lc+3][lr] = b0.w;
        Bs[lc+16][lr] = b1.x; Bs[lc+17][lr] = b1.y; Bs[lc+18][lr] = b1.z; Bs[lc+19][lr] = b1.w;
        __syncthreads();
        #pragma unroll
        for (int kk = 0; kk < 32; kk++) {
            float4 av = *(const float4*)&As[kk][ty << 2];
            float4 bv = *(const float4*)&Bs[kk][tx << 2];
            float a[4] = {av.x, av.y, av.z, av.w};
            float b[4] = {bv.x, bv.y, bv.z, bv.w};
            #pragma unroll
            for (int i = 0; i < 4; i++)
                #pragma unroll
                for (int j = 0; j < 4; j++)
                    acc[i][j] = fmaf(a[i], b[j], acc[i][j]);
        }
    }

    const int c0 = n0 + (tx << 2);
    const float4 bv4 = *(const float4*)&bias[c0];
    #pragma unroll
    for (int i = 0; i < 4; i++) {
        int m = m0 + (ty << 2) + i;
        float4 v;
        v.x = acc[i][0] + bv4.x; v.y = acc[i][1] + bv4.y;
        v.z = acc[i][2] + bv4.z; v.w = acc[i][3] + bv4.w;
        *(float4*)&out[m * NC + c0] = v;
    }
}

// ---------------------------------------------------------------------------
// Fused attention: one block per (b,h). 192 threads = 3 waves.
// K staged in LDS (swizzled, conflict-free b128). Each wave processes tiles
// of 4 queries; per lane 4 keys (m = lane+64j), 4-d vector steps: 64 FMA per
// 8 LDS reads. Softmax via wave shfl. P via LDS (broadcast b128 reads), V
// streamed coalesced from global (L2-resident, 50 KB per (b,h)).
// ---------------------------------------------------------------------------
__global__ __launch_bounds__(192) void attn_kernel(
    const float* __restrict__ qb, const float* __restrict__ kb,
    const float* __restrict__ vb, const float* __restrict__ table,
    const int* __restrict__ rel_index, float* __restrict__ ab)
{
    __shared__ float Ksh[NN * HD];      // swizzled: row m, float4-col (d4+m)&15
    __shared__ float Qsh[3][4 * HD];    // per wave: 4 queries x 64
    __shared__ float Psh[3][4][200];    // per wave: 4 queries x keys (padded)

    const int bh = blockIdx.x;
    const int b = bh / NH, h = bh % NH;
    const int tid = threadIdx.x;
    const int w = tid >> 6, lane = tid & 63;
    const int base = bh * (NN * HD);
    const float* kg = kb + base;
    const float* vg = vb + base;
    const float* qg = qb + base;

    // stage K with +m swizzle on the float4 column (conflict-free b128 reads)
    for (int i4 = tid; i4 < NN * 16; i4 += 192) {
        int m = i4 >> 4, dd = i4 & 15;
        float4 val = *(const float4*)(kg + m * HD + dd * 4);
        int sd = (dd + m) & 15;
        *(float4*)&Ksh[m * HD + sd * 4] = val;
    }
    __syncthreads();

    float* qs = Qsh[w];
    float* pw0 = Psh[w][0]; float* pw1 = Psh[w][1];
    float* pw2 = Psh[w][2]; float* pw3 = Psh[w][3];

    for (int t = w; t < 50; t += 3) {       // 50 query tiles of 4
        // load Q tile (clamped for tail)
        #pragma unroll
        for (int qi = 0; qi < 4; qi++) {
            int n = t * 4 + qi; if (n > 196) n = 196;
            qs[qi * HD + lane] = qg[n * HD + lane];
        }

        // init scores with relative-position bias (invalid keys -> -1e30)
        float s[4][4];
        #pragma unroll
        for (int qi = 0; qi < 4; qi++) {
            int n = t * 4 + qi; if (n > 196) n = 196;
            const int* ri = rel_index + n * NN;
            #pragma unroll
            for (int j = 0; j < 4; j++) {
                int m = lane + 64 * j;
                s[qi][j] = (m < NN) ? table[ri[m] * NH + h] : -1e30f;
            }
        }

        int mrow[4];
        #pragma unroll
        for (int j = 0; j < 4; j++) {
            int m = lane + 64 * j; mrow[j] = (m < NN) ? m : 196;  // clamp (|qk|<<1e30)
        }

        // scores: Q·K^T, 4 d's per step
        #pragma unroll 4
        for (int d4 = 0; d4 < 16; d4++) {
            float4 kx[4];
            #pragma unroll
            for (int j = 0; j < 4; j++) {
                int sd = (d4 + mrow[j]) & 15;
                kx[j] = *(const float4*)&Ksh[mrow[j] * HD + sd * 4];
            }
            #pragma unroll
            for (int qi = 0; qi < 4; qi++) {
                float4 qv = *(const float4*)&qs[qi * HD + d4 * 4];
                #pragma unroll
                for (int j = 0; j < 4; j++) {
                    s[qi][j] = fmaf(qv.x, kx[j].x, s[qi][j]);
                    s[qi][j] = fmaf(qv.y, kx[j].y, s[qi][j]);
                    s[qi][j] = fmaf(qv.z, kx[j].z, s[qi][j]);
                    s[qi][j] = fmaf(qv.w, kx[j].w, s[qi][j]);
                }
            }
        }

        // softmax per query row (across all 64 lanes x 4 key-slots)
        #pragma unroll
        for (int qi = 0; qi < 4; qi++) {
            float mx = fmaxf(fmaxf(s[qi][0], s[qi][1]), fmaxf(s[qi][2], s[qi][3]));
            #pragma unroll
            for (int off = 32; off > 0; off >>= 1)
                mx = fmaxf(mx, __shfl_xor(mx, off));
            float e[4];
            e[0] = __expf(s[qi][0] - mx); e[1] = __expf(s[qi][1] - mx);
            e[2] = __expf(s[qi][2] - mx); e[3] = __expf(s[qi][3] - mx);
            float sum = (e[0] + e[1]) + (e[2] + e[3]);
            #pragma unroll
            for (int off = 32; off > 0; off >>= 1)
                sum += __shfl_xor(sum, off);
            float inv = 1.0f / sum;
            float* pw = Psh[w][qi];
            #pragma unroll
            for (int j = 0; j < 4; j++) {
                int m = lane + 64 * j;
                if (m < 200) pw[m] = e[j] * inv;    // m in [197,200) gets 0
            }
        }

        // P·V: lane = output d; V read coalesced from global
        float o[4] = {0.f, 0.f, 0.f, 0.f};
        #pragma unroll 2
        for (int s4 = 0; s4 < 49; s4++) {
            const int mb = s4 * 4;
            float4 P0 = *(const float4*)&pw0[mb];
            float4 P1 = *(const float4*)&pw1[mb];
            float4 P2 = *(const float4*)&pw2[mb];
            float4 P3 = *(const float4*)&pw3[mb];
            const float* vp = vg + mb * HD + lane;
            float v0 = vp[0], v1 = vp[64], v2 = vp[128], v3 = vp[192];
            o[0] = fmaf(P0.x, v0, fmaf(P0.y, v1, fmaf(P0.z, v2, fmaf(P0.w, v3, o[0]))));
            o[1] = fmaf(P1.x, v0, fmaf(P1.y, v1, fmaf(P1.z, v2, fmaf(P1.w, v3, o[1]))));
            o[2] = fmaf(P2.x, v0, fmaf(P2.y, v1, fmaf(P2.z, v2, fmaf(P2.w, v3, o[2]))));
            o[3] = fmaf(P3.x, v0, fmaf(P3.y, v1, fmaf(P3.z, v2, fmaf(P3.w, v3, o[3]))));
        }
        {   // tail key m = 196
            float v0 = vg[196 * HD + lane];
            o[0] = fmaf(pw0[196], v0, o[0]);
            o[1] = fmaf(pw1[196], v0, o[1]);
            o[2] = fmaf(pw2[196], v0, o[2]);
            o[3] = fmaf(pw3[196], v0, o[3]);
        }

        // write attn output in [B,N,C] layout for the proj GEMM
        #pragma unroll
        for (int qi = 0; qi < 4; qi++) {
            int n = t * 4 + qi;
            if (n < NN) ab[(b * NN + n) * NC + h * HD + lane] = o[qi];
        }
    }
}

// ---------------------------------------------------------------------------
extern "C" void kernel_launch(void* const* d_in, const int* in_sizes, int n_in,
                              void* d_out, int out_size, void* d_ws, size_t ws_size,
                              hipStream_t stream)
{
    const float* x        = (const float*)d_in[0];
    const float* table    = (const float*)d_in[1];
    const float* w_qkv    = (const float*)d_in[2];
    const float* w_proj   = (const float*)d_in[3];
    const float* b_proj   = (const float*)d_in[4];
    const int*   rel_idx  = (const int*)d_in[5];
    float* out = (float*)d_out;

    const size_t SZ = (size_t)NB * NH * NN * HD;   // 9,682,944 floats
    float* qb = (float*)d_ws;
    float* kb = qb + SZ;
    float* vb = kb + SZ;
    float* ab = vb + SZ;                            // [B,N,C]

    gemm_qkv_kernel<<<dim3(197, 36), 256, 0, stream>>>(x, w_qkv, qb, kb, vb);
    attn_kernel<<<dim3(NB * NH), 192, 0, stream>>>(qb, kb, vb, table, rel_idx, ab);
    gemm_proj_kernel<<<dim3(197, 12), 256, 0, stream>>>(ab, w_proj, b_proj, out);
}